// Round 6
// baseline (327.731 us; speedup 1.0000x reference)
//
#include <hip/hip_runtime.h>
#include <hip/hip_bf16.h>
#include <math.h>

#define SS 200
#define BB 1024
#define DD 128
#define FF 512
#define LL1 80
#define LL2 40
#define PP (SS*BB)
#define MASK_FILL_F (-4294967295.0f)
#define NTILE 13            // 13 s-tiles of 16 rows = 208 (200 live)

typedef short bf16x8 __attribute__((ext_vector_type(8)));
typedef float f32x4  __attribute__((ext_vector_type(4)));

static __device__ __forceinline__ unsigned short f2bf(float x) {
    __hip_bfloat16 h = __float2bfloat16(x);
    return *reinterpret_cast<unsigned short*>(&h);
}
static __device__ __forceinline__ float bf2f(unsigned short u) {
    __hip_bfloat16 h = *reinterpret_cast<__hip_bfloat16*>(&u);
    return __bfloat162float(h);
}
// truncation split: hi = top 16 bits, lo = bf16(x - hi). |err| ~ 2^-16 rel.
static __device__ __forceinline__ void split8(const float* x, bf16x8& ah, bf16x8& al) {
#pragma unroll
    for (int j = 0; j < 8; ++j) {
        unsigned u = __float_as_uint(x[j]);
        ah[j] = (short)(u >> 16);
        float hi = __uint_as_float(u & 0xffff0000u);
        al[j] = (short)f2bf(x[j] - hi);
    }
}
static __device__ __forceinline__ float fast_sigmoid(float t) {
    return __builtin_amdgcn_rcpf(1.f + __expf(-t));
}

// ---------------------------------------------------------------------------
// Merged prep. blocks 0-29: W1 fold+split -> bfr1 phase-major:
//   fid = kt*30 + (seg*2+hl)*5 + nt   (per-kt 30-fid chunk contiguous)
// blocks 30-34: W2 pad+split -> bfr2, fid2 = (kt*3+nt)*2+hl.
// block 35: mask layout detect (wave-parallel).
__global__ void k_prep_all(const float* __restrict__ W1, const float* __restrict__ W2,
                           const unsigned char* __restrict__ mask,
                           unsigned short* __restrict__ bfr1,
                           unsigned short* __restrict__ bfr2, int* __restrict__ flag) {
    const int blk = blockIdx.x;
    if (blk == 35) {
        if (threadIdx.x < 64) {
            const uchar4 u = ((const uchar4*)mask)[threadIdx.x];
            const bool f = ((u.y | u.z) | u.w) != 0;
            const unsigned long long anyf = __ballot(f);
            if (threadIdx.x == 0) *flag = (anyf != 0ull) ? 1 : 0;
        }
        return;
    }
    if (blk < 30) {
        int t = blk * 256 + threadIdx.x;
        if (t >= 120 * 64) return;
        int lane = t & 63;
        int fid  = t >> 6;
        int nt   = fid % 5;
        int hl   = (fid / 5) % 2;
        int step = (fid / 10) % 6;
        int h    = fid / 60;
        int ktL  = step / 3;
        int seg  = step - 3 * ktL;
        int kt   = h * 2 + ktL;
        int n     = nt * 16 + (lane & 15);
        int kbase = kt * 32 + (lane >> 4) * 8;
        unsigned short* o = bfr1 + (size_t)t * 8;
#pragma unroll
        for (int j = 0; j < 8; ++j) {
            int k = kbase + j;
            float w;
            if (seg == 0)      w = W1[k * LL1 + n] + W1[(384 + k) * LL1 + n];
            else if (seg == 1) w = W1[(128 + k) * LL1 + n] - W1[(384 + k) * LL1 + n];
            else               w = W1[(256 + k) * LL1 + n];
            unsigned short hb = f2bf(w);
            o[j] = (hl == 0) ? hb : f2bf(w - bf2f(hb));
        }
    } else {
        int t = (blk - 30) * 256 + threadIdx.x;
        if (t >= 18 * 64) return;
        int lane = t & 63;
        int fid  = t >> 6;
        int hl   = fid & 1;
        int nt   = (fid >> 1) % 3;
        int kt   = fid / 6;
        int n  = nt * 16 + (lane & 15);
        int kb = kt * 32 + (lane >> 4) * 8;
        unsigned short* o = bfr2 + (size_t)t * 8;
#pragma unroll
        for (int j = 0; j < 8; ++j) {
            int k = kb + j;
            float w = (k < LL1 && n < LL2) ? W2[k * LL2 + n] : 0.f;
            unsigned short hb = f2bf(w);
            o[j] = (hl == 0) ? hb : f2bf(w - bf2f(hb));
        }
    }
}

// ---------------------------------------------------------------------------
// K1: z1[p][l] = ([q|f|q*f] @ foldedW1 + b1). NO LDS, NO BARRIERS: B-frags
// read directly from global. bfr1 is 120 KB = permanently L2-resident (every
// block reads all of it); each 30-KB kt-chunk fits the 32-KB L1, so the 4
// waves of a block hit L1 on re-reads. Each fragment read is a coalesced
// 1-KB wave transaction (lane*16 B). Straight-line full unroll lets the
// compiler pipeline seg n+1 B-loads under seg n MFMAs; occupancy is
// VGPR-limited (~4 waves/SIMD) instead of LDS-limited, with no lockstep
// barrier drains. (Round 2-3 lesson: NEVER use launch_bounds (.,4) — it
// clamps VGPR to 64 and spills; (256,2) caps at 256.)
__global__ __launch_bounds__(256, 2) void k1_mfma(
    const float* __restrict__ query, const float* __restrict__ facts,
    const unsigned short* __restrict__ bfr, const float* __restrict__ b1,
    float* __restrict__ z1) {
    const int tid  = threadIdx.x;
    const int lane = tid & 63;
    const int m    = lane & 15;
    const int quad = lane >> 4;
    const int pw   = blockIdx.x * 128 + (tid >> 6) * 32;

    f32x4 acc[2][5];
#pragma unroll
    for (int t = 0; t < 2; ++t)
#pragma unroll
        for (int nt = 0; nt < 5; ++nt) acc[t][nt] = (f32x4){0.f, 0.f, 0.f, 0.f};

    int pr[2], qr[2];
#pragma unroll
    for (int t = 0; t < 2; ++t) {
        pr[t] = pw + t * 16 + m;
        qr[t] = pr[t] / SS;
    }

#pragma unroll
    for (int kt = 0; kt < 4; ++kt) {
        // A burst-load for this kt
        const int dbase = kt * 32 + quad * 8;
        float q8[2][8], f8[2][8];
#pragma unroll
        for (int t = 0; t < 2; ++t) {
            const float* qp = query + (size_t)qr[t] * DD + dbase;
            const float* fp = facts + (size_t)pr[t] * DD + dbase;
            *(float4*)&q8[t][0] = *(const float4*)qp;
            *(float4*)&q8[t][4] = *(const float4*)(qp + 4);
            *(float4*)&f8[t][0] = *(const float4*)fp;
            *(float4*)&f8[t][4] = *(const float4*)(fp + 4);
        }
#pragma unroll
        for (int seg = 0; seg < 3; ++seg) {
            // B-frags straight from global (L1/L2-hot, coalesced 1 KB/frag)
            const unsigned short* bp =
                bfr + (size_t)(kt * 30 + seg * 10) * 512 + lane * 8;
            bf16x8 Bh[5], Bl[5];
#pragma unroll
            for (int nt = 0; nt < 5; ++nt) {
                Bh[nt] = *(const bf16x8*)(bp + (size_t)nt * 512);
                Bl[nt] = *(const bf16x8*)(bp + (size_t)(5 + nt) * 512);
            }
#pragma unroll
            for (int t = 0; t < 2; ++t) {
                float x8[8];
#pragma unroll
                for (int j = 0; j < 8; ++j)
                    x8[j] = (seg == 0) ? q8[t][j]
                          : (seg == 1 ? f8[t][j] : q8[t][j] * f8[t][j]);
                bf16x8 ah, al;
                split8(x8, ah, al);
#pragma unroll
                for (int nt = 0; nt < 5; ++nt) {
                    acc[t][nt] = __builtin_amdgcn_mfma_f32_16x16x32_bf16(ah, Bh[nt], acc[t][nt], 0, 0, 0);
                    acc[t][nt] = __builtin_amdgcn_mfma_f32_16x16x32_bf16(al, Bh[nt], acc[t][nt], 0, 0, 0);
                    acc[t][nt] = __builtin_amdgcn_mfma_f32_16x16x32_bf16(ah, Bl[nt], acc[t][nt], 0, 0, 0);
                }
            }
        }
    }
    // C/D layout: col = lane&15, row = quad*4 + reg. Coalesced [p][l] write.
#pragma unroll
    for (int t = 0; t < 2; ++t)
#pragma unroll
        for (int nt = 0; nt < 5; ++nt) {
            const int n = nt * 16 + m;
            const float bias = b1[n];
#pragma unroll
            for (int r = 0; r < 4; ++r)
                z1[(size_t)(pw + t * 16 + quad * 4 + r) * LL1 + n] = acc[t][nt][r] + bias;
        }
}

// ---------------------------------------------------------------------------
// K_light: per-b tail (single column, 72 KB LDS — the round-5-verified
// version, unchanged). Stage z1 rows s*1024+b (320 B chunks) -> LDS stride
// 81, stats1 -> dice1+GEMM2 (B2 direct from L2-hot bfr2) -> z2 (stride 41)
// -> stats2 -> dice2 + W3 dot -> masked softmax -> wgt to wbufT.
__global__ __launch_bounds__(512) void k_light(
    const float* __restrict__ z1, const unsigned short* __restrict__ bfr2,
    const float* __restrict__ a1, const float* __restrict__ b2,
    const float* __restrict__ a2, const float* __restrict__ W3,
    const float* __restrict__ b3, const void* __restrict__ mask,
    const int* __restrict__ flag, float* __restrict__ wbufT) {
    const int tid  = threadIdx.x;
    const int w    = tid >> 6;
    const int lane = tid & 63;
    const int m    = lane & 15;
    const int quad = lane >> 4;
    const int b    = blockIdx.x;

    __shared__ __align__(16) float z1f[NTILE * 16 * 81 + 16];  // 208 rows x 81 (+pad)
    __shared__ float psum[480], pssq[480];
    __shared__ float smean[LL1], sistd[LL1];
    __shared__ float sw3[LL2];
    __shared__ float red[8];

    // stage: 200 rows x 5 float4 (320 B contiguous per row) -> stride-81 rows
    {
        for (int i = tid; i < SS * 20; i += 512) {
            const int s = i / 20;
            const int o = i - s * 20;
            float4 v = ((const float4*)z1)[(size_t)(s * BB + b) * 20 + o];
            float* d = &z1f[s * 81 + o * 4];
            d[0] = v.x; d[1] = v.y; d[2] = v.z; d[3] = v.w;
        }
        // zero pad rows 200..207 (read by GEMM2 A-fragments, outputs discarded)
        for (int i = tid; i < 8 * 81 + 16; i += 512) z1f[SS * 81 + i] = 0.f;
    }
    __syncthreads();

    // stats1 over s (per l), 6 chunks x 80 cols
    if (tid < 480) {
        const int l = tid % LL1, c = tid / LL1;
        const int s0 = c * 34;
        const int s1 = (s0 + 34 < SS) ? s0 + 34 : SS;
        float sum = 0.f, ssq = 0.f;
        for (int s = s0; s < s1; ++s) {
            float v = z1f[s * 81 + l];
            sum += v;
            ssq = fmaf(v, v, ssq);
        }
        psum[c * LL1 + l] = sum;
        pssq[c * LL1 + l] = ssq;
    }
    __syncthreads();
    if (tid < LL1) {
        float sum = 0.f, ssq = 0.f;
#pragma unroll
        for (int c = 0; c < 6; ++c) {
            sum += psum[c * LL1 + tid];
            ssq += pssq[c * LL1 + tid];
        }
        float mn  = sum * (1.f / SS);
        float var = (ssq - (float)SS * mn * mn) * (1.f / (SS - 1));
        smean[tid] = mn;
        sistd[tid] = rsqrtf(var);
    }
    __syncthreads();

    // GEMM2: dice1-on-load, K 80->96, N 40->48. 8 waves x 2 tiles {w, w+8}.
    const float alpha1 = *a1;
    f32x4 acc2[2][3];
#pragma unroll
    for (int t = 0; t < 2; ++t)
#pragma unroll
        for (int nt = 0; nt < 3; ++nt) acc2[t][nt] = (f32x4){0.f, 0.f, 0.f, 0.f};

    int tile[2];
    bool tl[2];
#pragma unroll
    for (int t = 0; t < 2; ++t) {
        tile[t] = t * 8 + w;
        tl[t]   = (tile[t] < NTILE);
    }

#pragma unroll
    for (int kt = 0; kt < 3; ++kt) {
        bf16x8 Bh[3], Bl[3];
#pragma unroll
        for (int nt = 0; nt < 3; ++nt) {     // 18 KB, L2-hot, read direct
            Bh[nt] = *(const bf16x8*)(bfr2 + (size_t)((kt * 3 + nt) * 2 + 0) * 512 + lane * 8);
            Bl[nt] = *(const bf16x8*)(bfr2 + (size_t)((kt * 3 + nt) * 2 + 1) * 512 + lane * 8);
        }
        const int kb = kt * 32 + quad * 8;
        const bool lv = (kt < 2 || quad < 2);   // k < 80
#pragma unroll
        for (int t = 0; t < 2; ++t) {
            if (!tl[t]) continue;
            float x8[8];
            if (lv) {
                const float* zr = &z1f[(tile[t] * 16 + m) * 81 + kb];
#pragma unroll
                for (int j = 0; j < 8; ++j) {
                    float v  = zr[j];
                    float pp = fast_sigmoid((v - smean[kb + j]) * sistd[kb + j]);
                    x8[j] = v * (alpha1 + (1.f - alpha1) * pp);
                }
            } else {
#pragma unroll
                for (int j = 0; j < 8; ++j) x8[j] = 0.f;
            }
            bf16x8 ah, al;
            split8(x8, ah, al);
#pragma unroll
            for (int nt = 0; nt < 3; ++nt) {
                acc2[t][nt] = __builtin_amdgcn_mfma_f32_16x16x32_bf16(ah, Bh[nt], acc2[t][nt], 0, 0, 0);
                acc2[t][nt] = __builtin_amdgcn_mfma_f32_16x16x32_bf16(al, Bh[nt], acc2[t][nt], 0, 0, 0);
                acc2[t][nt] = __builtin_amdgcn_mfma_f32_16x16x32_bf16(ah, Bl[nt], acc2[t][nt], 0, 0, 0);
            }
        }
    }
    __syncthreads();                         // all z1 reads done -> reuse as z2

    {
        float b2v[3];
#pragma unroll
        for (int nt = 0; nt < 3; ++nt) {
            const int n = nt * 16 + m;
            b2v[nt] = (n < LL2) ? b2[n] : 0.f;
        }
#pragma unroll
        for (int t = 0; t < 2; ++t) {
            if (!tl[t]) continue;
#pragma unroll
            for (int r = 0; r < 4; ++r) {
                const int srow = tile[t] * 16 + quad * 4 + r;
                if (srow >= SS) continue;
#pragma unroll
                for (int nt = 0; nt < 3; ++nt) {
                    const int n = nt * 16 + m;
                    if (n < LL2) z1f[srow * 41 + n] = acc2[t][nt][r] + b2v[nt];
                }
            }
        }
    }
    __syncthreads();

    // stats2, 12 chunks x 40 cols
    if (tid < 480) {
        const int l = tid % LL2, c = tid / LL2;
        const int s0 = c * 17;
        const int s1 = (s0 + 17 < SS) ? s0 + 17 : SS;
        float sum = 0.f, ssq = 0.f;
        for (int s = s0; s < s1; ++s) {
            float v = z1f[s * 41 + l];
            sum += v;
            ssq = fmaf(v, v, ssq);
        }
        psum[c * LL2 + l] = sum;
        pssq[c * LL2 + l] = ssq;
    }
    __syncthreads();
    if (tid < LL2) {
        float sum = 0.f, ssq = 0.f;
#pragma unroll
        for (int c = 0; c < 12; ++c) {
            sum += psum[c * LL2 + tid];
            ssq += pssq[c * LL2 + tid];
        }
        float mn  = sum * (1.f / SS);
        float var = (ssq - (float)SS * mn * mn) * (1.f / (SS - 1));
        smean[tid] = mn;
        sistd[tid] = rsqrtf(var);
        sw3[tid]   = W3[tid];
    }
    __syncthreads();

    // dice2 + W3 dot + masked softmax over s
    const float alpha2 = *a2;
    const int boolLayout = *flag;
    float logit = -3.0e38f;
    if (tid < SS) {
        float dot = b3[0];
#pragma unroll
        for (int k = 0; k < LL2; ++k) {
            float v  = z1f[tid * 41 + k];
            float pp = fast_sigmoid((v - smean[k]) * sistd[k]);
            float hh = v * (pp + alpha2 * (1.f - pp));
            dot = fmaf(hh, sw3[k], dot);
        }
        const int mi = tid * BB + b;
        const bool mk = boolLayout ? (((const unsigned char*)mask)[mi] != 0)
                                   : (((const int*)mask)[mi] != 0);
        logit = mk ? dot : MASK_FILL_F;
    }
    float v = logit;
#pragma unroll
    for (int off = 1; off < 64; off <<= 1) v = fmaxf(v, __shfl_xor(v, off, 64));
    if (lane == 0) red[w] = v;
    __syncthreads();
    float smax = red[0];
#pragma unroll
    for (int i = 1; i < 8; ++i) smax = fmaxf(smax, red[i]);
    __syncthreads();
    const float e = (tid < SS) ? __expf(logit - smax) : 0.f;
    v = e;
#pragma unroll
    for (int off = 1; off < 64; off <<= 1) v += __shfl_xor(v, off, 64);
    if (lane == 0) red[w] = v;
    __syncthreads();
    float ssum = red[0];
#pragma unroll
    for (int i = 1; i < 8; ++i) ssum += red[i];
    const float inv = __builtin_amdgcn_rcpf(ssum);
    if (tid < SS) wbufT[(size_t)b * SS + tid] = e * inv;
}

// ---------------------------------------------------------------------------
// K4: out[s][b][d] = wbufT[b][s] * facts[s][b][d]  (fully coalesced stream)
__global__ __launch_bounds__(256) void k4_scale(
    const float* __restrict__ wbufT, const float* __restrict__ facts,
    float* __restrict__ out) {
    int i = blockIdx.x * 256 + threadIdx.x;   // float4 index
    int p = i >> 5;                           // (s*B + b), 32 float4 per row
    float w = wbufT[(size_t)(p & (BB - 1)) * SS + (p >> 10)];
    float4 f = ((const float4*)facts)[i];
    float4 o;
    o.x = f.x * w; o.y = f.y * w; o.z = f.z * w; o.w = f.w * w;
    ((float4*)out)[i] = o;
}

// ---------------------------------------------------------------------------
extern "C" void kernel_launch(void* const* d_in, const int* in_sizes, int n_in,
                              void* d_out, int out_size, void* d_ws, size_t ws_size,
                              hipStream_t stream) {
    const float* query = (const float*)d_in[0];
    const float* facts = (const float*)d_in[1];
    const void*  mask  = d_in[2];
    const float* W1 = (const float*)d_in[3];
    const float* b1 = (const float*)d_in[4];
    const float* a1 = (const float*)d_in[5];
    const float* W2 = (const float*)d_in[6];
    const float* b2 = (const float*)d_in[7];
    const float* a2 = (const float*)d_in[8];
    const float* W3 = (const float*)d_in[9];
    const float* b3 = (const float*)d_in[10];
    float* out = (float*)d_out;

    // d_out scratch (26,214,400 floats; all dead before k4 overwrites):
    //   z1 [0, 16,384,000)  layout [p][l]
    //   bfr1 @ float-offset 24,739,840 (122,880 B) ; bfr2 @ 24,801,280 (18,432 B)
    float* z1 = out;
    unsigned short* bfr1 = (unsigned short*)(out + 24739840);
    unsigned short* bfr2 = (unsigned short*)(out + 24801280);
    // d_ws: wbufT (819,200 B) @0 ; flag @900K
    float* wbufT = (float*)d_ws;
    int*   flag  = (int*)((char*)d_ws + 900 * 1024);

    k_prep_all<<<36, 256, 0, stream>>>(W1, W2, (const unsigned char*)mask, bfr1, bfr2, flag);
    k1_mfma<<<PP / 128, 256, 0, stream>>>(query, facts, bfr1, b1, z1);
    k_light<<<BB, 512, 0, stream>>>(z1, bfr2, a1, b2, a2, W3, b3, mask, flag, wbufT);
    k4_scale<<<(PP * DD) / (256 * 4), 256, 0, stream>>>(wbufT, facts, out);
}

// Round 7
// 310.891 us; speedup vs baseline: 1.0542x; 1.0542x over previous
//
#include <hip/hip_runtime.h>
#include <hip/hip_bf16.h>
#include <math.h>

#define SS 200
#define BB 1024
#define DD 128
#define FF 512
#define LL1 80
#define LL2 40
#define PP (SS*BB)
#define MASK_FILL_F (-4294967295.0f)
#define NTILE 13            // 13 s-tiles of 16 rows = 208 (200 live)

typedef short bf16x8 __attribute__((ext_vector_type(8)));
typedef float f32x4  __attribute__((ext_vector_type(4)));

static __device__ __forceinline__ unsigned short f2bf(float x) {
    __hip_bfloat16 h = __float2bfloat16(x);
    return *reinterpret_cast<unsigned short*>(&h);
}
static __device__ __forceinline__ float bf2f(unsigned short u) {
    __hip_bfloat16 h = *reinterpret_cast<__hip_bfloat16*>(&u);
    return __bfloat162float(h);
}
// truncation split: hi = top 16 bits, lo = bf16(x - hi). |err| ~ 2^-16 rel.
static __device__ __forceinline__ void split8(const float* x, bf16x8& ah, bf16x8& al) {
#pragma unroll
    for (int j = 0; j < 8; ++j) {
        unsigned u = __float_as_uint(x[j]);
        ah[j] = (short)(u >> 16);
        float hi = __uint_as_float(u & 0xffff0000u);
        al[j] = (short)f2bf(x[j] - hi);
    }
}
static __device__ __forceinline__ float fast_sigmoid(float t) {
    return __builtin_amdgcn_rcpf(1.f + __expf(-t));
}

// ---------------------------------------------------------------------------
// Merged prep. blocks 0-29: W1 fold+split -> bfr1 phase-major:
//   fid = kt*30 + (seg*2+hl)*5 + nt   (per-kt 30-fid chunk contiguous)
// blocks 30-34: W2 pad+split -> bfr2, fid2 = (kt*3+nt)*2+hl.
// block 35: mask layout detect (wave-parallel).
__global__ void k_prep_all(const float* __restrict__ W1, const float* __restrict__ W2,
                           const unsigned char* __restrict__ mask,
                           unsigned short* __restrict__ bfr1,
                           unsigned short* __restrict__ bfr2, int* __restrict__ flag) {
    const int blk = blockIdx.x;
    if (blk == 35) {
        if (threadIdx.x < 64) {
            const uchar4 u = ((const uchar4*)mask)[threadIdx.x];
            const bool f = ((u.y | u.z) | u.w) != 0;
            const unsigned long long anyf = __ballot(f);
            if (threadIdx.x == 0) *flag = (anyf != 0ull) ? 1 : 0;
        }
        return;
    }
    if (blk < 30) {
        int t = blk * 256 + threadIdx.x;
        if (t >= 120 * 64) return;
        int lane = t & 63;
        int fid  = t >> 6;
        int nt   = fid % 5;
        int hl   = (fid / 5) % 2;
        int step = (fid / 10) % 6;
        int h    = fid / 60;
        int ktL  = step / 3;
        int seg  = step - 3 * ktL;
        int kt   = h * 2 + ktL;
        int n     = nt * 16 + (lane & 15);
        int kbase = kt * 32 + (lane >> 4) * 8;
        unsigned short* o = bfr1 + (size_t)t * 8;
#pragma unroll
        for (int j = 0; j < 8; ++j) {
            int k = kbase + j;
            float w;
            if (seg == 0)      w = W1[k * LL1 + n] + W1[(384 + k) * LL1 + n];
            else if (seg == 1) w = W1[(128 + k) * LL1 + n] - W1[(384 + k) * LL1 + n];
            else               w = W1[(256 + k) * LL1 + n];
            unsigned short hb = f2bf(w);
            o[j] = (hl == 0) ? hb : f2bf(w - bf2f(hb));
        }
    } else {
        int t = (blk - 30) * 256 + threadIdx.x;
        if (t >= 18 * 64) return;
        int lane = t & 63;
        int fid  = t >> 6;
        int hl   = fid & 1;
        int nt   = (fid >> 1) % 3;
        int kt   = fid / 6;
        int n  = nt * 16 + (lane & 15);
        int kb = kt * 32 + (lane >> 4) * 8;
        unsigned short* o = bfr2 + (size_t)t * 8;
#pragma unroll
        for (int j = 0; j < 8; ++j) {
            int k = kb + j;
            float w = (k < LL1 && n < LL2) ? W2[k * LL2 + n] : 0.f;
            unsigned short hb = f2bf(w);
            o[j] = (hl == 0) ? hb : f2bf(w - bf2f(hb));
        }
    }
}

// ---------------------------------------------------------------------------
// K1: z1[p][l] = ([q|f|q*f] @ foldedW1 + b1), p-tiled, coalesced facts reads
// and coalesced z1 writes. DOUBLE-BUFFERED pipeline: 2 x 30720 B LDS buffers,
// kt fully unrolled; each iteration issues A(kt+1) register prefetch and
// stages B(kt+1) into the other buffer BEFORE computing kt, one barrier per
// kt. Loads get a full compute phase in flight (round 5's stage->barrier->
// consume gave them ~zero). Round-6 lesson: B must stay LDS-staged (global-
// direct B cost +20 us). Round 2-3 lesson: launch_bounds (.,4) clamps VGPR
// to 64 and spills ~175 MB; (256,2) caps at 256.
__global__ __launch_bounds__(256, 2) void k1_mfma(
    const float* __restrict__ query, const float* __restrict__ facts,
    const unsigned short* __restrict__ bfr, const float* __restrict__ b1,
    float* __restrict__ z1) {
    const int tid  = threadIdx.x;
    const int lane = tid & 63;
    const int m    = lane & 15;
    const int quad = lane >> 4;
    const int pw   = blockIdx.x * 128 + (tid >> 6) * 32;

    __shared__ __align__(16) unsigned short lbuf[2][15360];   // 2 x 30720 B

    f32x4 acc[2][5];
#pragma unroll
    for (int t = 0; t < 2; ++t)
#pragma unroll
        for (int nt = 0; nt < 5; ++nt) acc[t][nt] = (f32x4){0.f, 0.f, 0.f, 0.f};

    int pr[2], qr[2];
#pragma unroll
    for (int t = 0; t < 2; ++t) {
        pr[t] = pw + t * 16 + m;
        qr[t] = pr[t] / SS;
    }

    float q8[2][8], f8[2][8];
    // prologue: A(0) + stage(0 -> buf0)
    {
        const int dbase = quad * 8;
#pragma unroll
        for (int t = 0; t < 2; ++t) {
            const float* qp = query + (size_t)qr[t] * DD + dbase;
            const float* fp = facts + (size_t)pr[t] * DD + dbase;
            *(float4*)&q8[t][0] = *(const float4*)qp;
            *(float4*)&q8[t][4] = *(const float4*)(qp + 4);
            *(float4*)&f8[t][0] = *(const float4*)fp;
            *(float4*)&f8[t][4] = *(const float4*)(fp + 4);
        }
        const int4* src = (const int4*)bfr;
#pragma unroll
        for (int it = 0; it < 8; ++it) {
            int idx = it * 256 + tid;
            if (idx < 1920) ((int4*)lbuf[0])[idx] = src[idx];
        }
    }
    __syncthreads();

#pragma unroll
    for (int kt = 0; kt < 4; ++kt) {
        float qn[2][8], fn[2][8];
        if (kt < 3) {
            // A(kt+1) register prefetch — lands under compute(kt)
            const int dbase = (kt + 1) * 32 + quad * 8;
#pragma unroll
            for (int t = 0; t < 2; ++t) {
                const float* qp = query + (size_t)qr[t] * DD + dbase;
                const float* fp = facts + (size_t)pr[t] * DD + dbase;
                *(float4*)&qn[t][0] = *(const float4*)qp;
                *(float4*)&qn[t][4] = *(const float4*)(qp + 4);
                *(float4*)&fn[t][0] = *(const float4*)fp;
                *(float4*)&fn[t][4] = *(const float4*)(fp + 4);
            }
            // stage B(kt+1) into the other buffer — overlaps compute(kt)
            const int4* src = (const int4*)bfr + (kt + 1) * 1920;
            int4* dst = (int4*)lbuf[(kt + 1) & 1];
#pragma unroll
            for (int it = 0; it < 8; ++it) {
                int idx = it * 256 + tid;
                if (idx < 1920) dst[idx] = src[idx];
            }
        }
        // compute(kt) from buf[kt&1]
        const unsigned short* cb = lbuf[kt & 1];
#pragma unroll
        for (int seg = 0; seg < 3; ++seg) {
            bf16x8 Bh[5], Bl[5];
#pragma unroll
            for (int nt = 0; nt < 5; ++nt) {
                Bh[nt] = *(const bf16x8*)&cb[((seg * 2 + 0) * 5 + nt) * 512 + lane * 8];
                Bl[nt] = *(const bf16x8*)&cb[((seg * 2 + 1) * 5 + nt) * 512 + lane * 8];
            }
#pragma unroll
            for (int t = 0; t < 2; ++t) {
                float x8[8];
#pragma unroll
                for (int j = 0; j < 8; ++j)
                    x8[j] = (seg == 0) ? q8[t][j]
                          : (seg == 1 ? f8[t][j] : q8[t][j] * f8[t][j]);
                bf16x8 ah, al;
                split8(x8, ah, al);
#pragma unroll
                for (int nt = 0; nt < 5; ++nt) {
                    acc[t][nt] = __builtin_amdgcn_mfma_f32_16x16x32_bf16(ah, Bh[nt], acc[t][nt], 0, 0, 0);
                    acc[t][nt] = __builtin_amdgcn_mfma_f32_16x16x32_bf16(al, Bh[nt], acc[t][nt], 0, 0, 0);
                    acc[t][nt] = __builtin_amdgcn_mfma_f32_16x16x32_bf16(ah, Bl[nt], acc[t][nt], 0, 0, 0);
                }
            }
        }
        if (kt < 3) {
            __syncthreads();   // staging(kt+1) visible; reads of buf[kt&1] retired
#pragma unroll
            for (int t = 0; t < 2; ++t)
#pragma unroll
                for (int j = 0; j < 8; ++j) {
                    q8[t][j] = qn[t][j];
                    f8[t][j] = fn[t][j];
                }
        }
    }
    // C/D layout: col = lane&15, row = quad*4 + reg. Coalesced [p][l] write.
#pragma unroll
    for (int t = 0; t < 2; ++t)
#pragma unroll
        for (int nt = 0; nt < 5; ++nt) {
            const int n = nt * 16 + m;
            const float bias = b1[n];
#pragma unroll
            for (int r = 0; r < 4; ++r)
                z1[(size_t)(pw + t * 16 + quad * 4 + r) * LL1 + n] = acc[t][nt][r] + bias;
        }
}

// ---------------------------------------------------------------------------
// K_light: per-b tail (single column, 72 KB LDS — the round-5-verified
// version, unchanged). Stage z1 rows s*1024+b (320 B chunks) -> LDS stride
// 81, stats1 -> dice1+GEMM2 (B2 direct from L2-hot bfr2) -> z2 (stride 41)
// -> stats2 -> dice2 + W3 dot -> masked softmax -> wgt to wbufT.
__global__ __launch_bounds__(512) void k_light(
    const float* __restrict__ z1, const unsigned short* __restrict__ bfr2,
    const float* __restrict__ a1, const float* __restrict__ b2,
    const float* __restrict__ a2, const float* __restrict__ W3,
    const float* __restrict__ b3, const void* __restrict__ mask,
    const int* __restrict__ flag, float* __restrict__ wbufT) {
    const int tid  = threadIdx.x;
    const int w    = tid >> 6;
    const int lane = tid & 63;
    const int m    = lane & 15;
    const int quad = lane >> 4;
    const int b    = blockIdx.x;

    __shared__ __align__(16) float z1f[NTILE * 16 * 81 + 16];  // 208 rows x 81 (+pad)
    __shared__ float psum[480], pssq[480];
    __shared__ float smean[LL1], sistd[LL1];
    __shared__ float sw3[LL2];
    __shared__ float red[8];

    // stage: 200 rows x 5 float4 (320 B contiguous per row) -> stride-81 rows
    {
        for (int i = tid; i < SS * 20; i += 512) {
            const int s = i / 20;
            const int o = i - s * 20;
            float4 v = ((const float4*)z1)[(size_t)(s * BB + b) * 20 + o];
            float* d = &z1f[s * 81 + o * 4];
            d[0] = v.x; d[1] = v.y; d[2] = v.z; d[3] = v.w;
        }
        // zero pad rows 200..207 (read by GEMM2 A-fragments, outputs discarded)
        for (int i = tid; i < 8 * 81 + 16; i += 512) z1f[SS * 81 + i] = 0.f;
    }
    __syncthreads();

    // stats1 over s (per l), 6 chunks x 80 cols
    if (tid < 480) {
        const int l = tid % LL1, c = tid / LL1;
        const int s0 = c * 34;
        const int s1 = (s0 + 34 < SS) ? s0 + 34 : SS;
        float sum = 0.f, ssq = 0.f;
        for (int s = s0; s < s1; ++s) {
            float v = z1f[s * 81 + l];
            sum += v;
            ssq = fmaf(v, v, ssq);
        }
        psum[c * LL1 + l] = sum;
        pssq[c * LL1 + l] = ssq;
    }
    __syncthreads();
    if (tid < LL1) {
        float sum = 0.f, ssq = 0.f;
#pragma unroll
        for (int c = 0; c < 6; ++c) {
            sum += psum[c * LL1 + tid];
            ssq += pssq[c * LL1 + tid];
        }
        float mn  = sum * (1.f / SS);
        float var = (ssq - (float)SS * mn * mn) * (1.f / (SS - 1));
        smean[tid] = mn;
        sistd[tid] = rsqrtf(var);
    }
    __syncthreads();

    // GEMM2: dice1-on-load, K 80->96, N 40->48. 8 waves x 2 tiles {w, w+8}.
    const float alpha1 = *a1;
    f32x4 acc2[2][3];
#pragma unroll
    for (int t = 0; t < 2; ++t)
#pragma unroll
        for (int nt = 0; nt < 3; ++nt) acc2[t][nt] = (f32x4){0.f, 0.f, 0.f, 0.f};

    int tile[2];
    bool tl[2];
#pragma unroll
    for (int t = 0; t < 2; ++t) {
        tile[t] = t * 8 + w;
        tl[t]   = (tile[t] < NTILE);
    }

#pragma unroll
    for (int kt = 0; kt < 3; ++kt) {
        bf16x8 Bh[3], Bl[3];
#pragma unroll
        for (int nt = 0; nt < 3; ++nt) {     // 18 KB, L2-hot, read direct
            Bh[nt] = *(const bf16x8*)(bfr2 + (size_t)((kt * 3 + nt) * 2 + 0) * 512 + lane * 8);
            Bl[nt] = *(const bf16x8*)(bfr2 + (size_t)((kt * 3 + nt) * 2 + 1) * 512 + lane * 8);
        }
        const int kb = kt * 32 + quad * 8;
        const bool lv = (kt < 2 || quad < 2);   // k < 80
#pragma unroll
        for (int t = 0; t < 2; ++t) {
            if (!tl[t]) continue;
            float x8[8];
            if (lv) {
                const float* zr = &z1f[(tile[t] * 16 + m) * 81 + kb];
#pragma unroll
                for (int j = 0; j < 8; ++j) {
                    float v  = zr[j];
                    float pp = fast_sigmoid((v - smean[kb + j]) * sistd[kb + j]);
                    x8[j] = v * (alpha1 + (1.f - alpha1) * pp);
                }
            } else {
#pragma unroll
                for (int j = 0; j < 8; ++j) x8[j] = 0.f;
            }
            bf16x8 ah, al;
            split8(x8, ah, al);
#pragma unroll
            for (int nt = 0; nt < 3; ++nt) {
                acc2[t][nt] = __builtin_amdgcn_mfma_f32_16x16x32_bf16(ah, Bh[nt], acc2[t][nt], 0, 0, 0);
                acc2[t][nt] = __builtin_amdgcn_mfma_f32_16x16x32_bf16(al, Bh[nt], acc2[t][nt], 0, 0, 0);
                acc2[t][nt] = __builtin_amdgcn_mfma_f32_16x16x32_bf16(ah, Bl[nt], acc2[t][nt], 0, 0, 0);
            }
        }
    }
    __syncthreads();                         // all z1 reads done -> reuse as z2

    {
        float b2v[3];
#pragma unroll
        for (int nt = 0; nt < 3; ++nt) {
            const int n = nt * 16 + m;
            b2v[nt] = (n < LL2) ? b2[n] : 0.f;
        }
#pragma unroll
        for (int t = 0; t < 2; ++t) {
            if (!tl[t]) continue;
#pragma unroll
            for (int r = 0; r < 4; ++r) {
                const int srow = tile[t] * 16 + quad * 4 + r;
                if (srow >= SS) continue;
#pragma unroll
                for (int nt = 0; nt < 3; ++nt) {
                    const int n = nt * 16 + m;
                    if (n < LL2) z1f[srow * 41 + n] = acc2[t][nt][r] + b2v[nt];
                }
            }
        }
    }
    __syncthreads();

    // stats2, 12 chunks x 40 cols
    if (tid < 480) {
        const int l = tid % LL2, c = tid / LL2;
        const int s0 = c * 17;
        const int s1 = (s0 + 17 < SS) ? s0 + 17 : SS;
        float sum = 0.f, ssq = 0.f;
        for (int s = s0; s < s1; ++s) {
            float v = z1f[s * 41 + l];
            sum += v;
            ssq = fmaf(v, v, ssq);
        }
        psum[c * LL2 + l] = sum;
        pssq[c * LL2 + l] = ssq;
    }
    __syncthreads();
    if (tid < LL2) {
        float sum = 0.f, ssq = 0.f;
#pragma unroll
        for (int c = 0; c < 12; ++c) {
            sum += psum[c * LL2 + tid];
            ssq += pssq[c * LL2 + tid];
        }
        float mn  = sum * (1.f / SS);
        float var = (ssq - (float)SS * mn * mn) * (1.f / (SS - 1));
        smean[tid] = mn;
        sistd[tid] = rsqrtf(var);
        sw3[tid]   = W3[tid];
    }
    __syncthreads();

    // dice2 + W3 dot + masked softmax over s
    const float alpha2 = *a2;
    const int boolLayout = *flag;
    float logit = -3.0e38f;
    if (tid < SS) {
        float dot = b3[0];
#pragma unroll
        for (int k = 0; k < LL2; ++k) {
            float v  = z1f[tid * 41 + k];
            float pp = fast_sigmoid((v - smean[k]) * sistd[k]);
            float hh = v * (pp + alpha2 * (1.f - pp));
            dot = fmaf(hh, sw3[k], dot);
        }
        const int mi = tid * BB + b;
        const bool mk = boolLayout ? (((const unsigned char*)mask)[mi] != 0)
                                   : (((const int*)mask)[mi] != 0);
        logit = mk ? dot : MASK_FILL_F;
    }
    float v = logit;
#pragma unroll
    for (int off = 1; off < 64; off <<= 1) v = fmaxf(v, __shfl_xor(v, off, 64));
    if (lane == 0) red[w] = v;
    __syncthreads();
    float smax = red[0];
#pragma unroll
    for (int i = 1; i < 8; ++i) smax = fmaxf(smax, red[i]);
    __syncthreads();
    const float e = (tid < SS) ? __expf(logit - smax) : 0.f;
    v = e;
#pragma unroll
    for (int off = 1; off < 64; off <<= 1) v += __shfl_xor(v, off, 64);
    if (lane == 0) red[w] = v;
    __syncthreads();
    float ssum = red[0];
#pragma unroll
    for (int i = 1; i < 8; ++i) ssum += red[i];
    const float inv = __builtin_amdgcn_rcpf(ssum);
    if (tid < SS) wbufT[(size_t)b * SS + tid] = e * inv;
}

// ---------------------------------------------------------------------------
// K4: out[s][b][d] = wbufT[b][s] * facts[s][b][d]  (fully coalesced stream)
__global__ __launch_bounds__(256) void k4_scale(
    const float* __restrict__ wbufT, const float* __restrict__ facts,
    float* __restrict__ out) {
    int i = blockIdx.x * 256 + threadIdx.x;   // float4 index
    int p = i >> 5;                           // (s*B + b), 32 float4 per row
    float w = wbufT[(size_t)(p & (BB - 1)) * SS + (p >> 10)];
    float4 f = ((const float4*)facts)[i];
    float4 o;
    o.x = f.x * w; o.y = f.y * w; o.z = f.z * w; o.w = f.w * w;
    ((float4*)out)[i] = o;
}

// ---------------------------------------------------------------------------
extern "C" void kernel_launch(void* const* d_in, const int* in_sizes, int n_in,
                              void* d_out, int out_size, void* d_ws, size_t ws_size,
                              hipStream_t stream) {
    const float* query = (const float*)d_in[0];
    const float* facts = (const float*)d_in[1];
    const void*  mask  = d_in[2];
    const float* W1 = (const float*)d_in[3];
    const float* b1 = (const float*)d_in[4];
    const float* a1 = (const float*)d_in[5];
    const float* W2 = (const float*)d_in[6];
    const float* b2 = (const float*)d_in[7];
    const float* a2 = (const float*)d_in[8];
    const float* W3 = (const float*)d_in[9];
    const float* b3 = (const float*)d_in[10];
    float* out = (float*)d_out;

    // d_out scratch (26,214,400 floats; all dead before k4 overwrites):
    //   z1 [0, 16,384,000)  layout [p][l]
    //   bfr1 @ float-offset 24,739,840 (122,880 B) ; bfr2 @ 24,801,280 (18,432 B)
    float* z1 = out;
    unsigned short* bfr1 = (unsigned short*)(out + 24739840);
    unsigned short* bfr2 = (unsigned short*)(out + 24801280);
    // d_ws: wbufT (819,200 B) @0 ; flag @900K
    float* wbufT = (float*)d_ws;
    int*   flag  = (int*)((char*)d_ws + 900 * 1024);

    k_prep_all<<<36, 256, 0, stream>>>(W1, W2, (const unsigned char*)mask, bfr1, bfr2, flag);
    k1_mfma<<<PP / 128, 256, 0, stream>>>(query, facts, bfr1, b1, z1);
    k_light<<<BB, 512, 0, stream>>>(z1, bfr2, a1, b2, a2, W3, b3, mask, flag, wbufT);
    k4_scale<<<(PP * DD) / (256 * 4), 256, 0, stream>>>(wbufT, facts, out);
}

// Round 8
// 298.866 us; speedup vs baseline: 1.0966x; 1.0402x over previous
//
#include <hip/hip_runtime.h>
#include <hip/hip_bf16.h>
#include <math.h>

#define SS 200
#define BB 1024
#define DD 128
#define FF 512
#define LL1 80
#define LL2 40
#define PP (SS*BB)
#define MASK_FILL_F (-4294967295.0f)
#define NTILE 13            // 13 s-tiles of 16 rows = 208 (200 live)

typedef short bf16x8 __attribute__((ext_vector_type(8)));
typedef float f32x4  __attribute__((ext_vector_type(4)));

static __device__ __forceinline__ unsigned short f2bf(float x) {
    __hip_bfloat16 h = __float2bfloat16(x);
    return *reinterpret_cast<unsigned short*>(&h);
}
static __device__ __forceinline__ float bf2f(unsigned short u) {
    __hip_bfloat16 h = *reinterpret_cast<__hip_bfloat16*>(&u);
    return __bfloat162float(h);
}
// truncation split: hi = top 16 bits, lo = bf16(x - hi). |err| ~ 2^-16 rel.
static __device__ __forceinline__ void split8(const float* x, bf16x8& ah, bf16x8& al) {
#pragma unroll
    for (int j = 0; j < 8; ++j) {
        unsigned u = __float_as_uint(x[j]);
        ah[j] = (short)(u >> 16);
        float hi = __uint_as_float(u & 0xffff0000u);
        al[j] = (short)f2bf(x[j] - hi);
    }
}
static __device__ __forceinline__ float fast_sigmoid(float t) {
    return __builtin_amdgcn_rcpf(1.f + __expf(-t));
}

// ---------------------------------------------------------------------------
// Merged prep.
//  blocks 0-19 : W1 fold+split -> bfr1, segs {f, q*f} only (q-part moves to U):
//                fid = kt*20 + (sg*2+hl)*5 + nt ; sg0: W1b-W1d, sg1: W1c
//  blocks 20-24: W2 pad+split -> bfr2, fid2 = (kt*3+nt)*2+hl
//  block  25   : mask layout detect (wave-parallel)
//  blocks 26+  : U[qr][n] = b1[n] + sum_k q[qr][k]*(W1a+W1d)[k][n]  (f32 exact;
//                1024 x 80, 3 qr-rows per block, n-coalesced W1 reads, L2-hot)
__global__ void k_prep_all(const float* __restrict__ W1, const float* __restrict__ W2,
                           const unsigned char* __restrict__ mask,
                           const float* __restrict__ query, const float* __restrict__ b1,
                           unsigned short* __restrict__ bfr1,
                           unsigned short* __restrict__ bfr2,
                           float* __restrict__ U, int* __restrict__ flag) {
    const int blk = blockIdx.x;
    if (blk < 20) {
        int t = blk * 256 + threadIdx.x;     // 80 fids x 64 lanes = 5120 threads
        int lane = t & 63;
        int fid  = t >> 6;
        int nt = fid % 5;
        int hl = (fid / 5) % 2;
        int sg = (fid / 10) % 2;
        int kt = fid / 20;
        int n     = nt * 16 + (lane & 15);
        int kbase = kt * 32 + (lane >> 4) * 8;
        unsigned short* o = bfr1 + (size_t)t * 8;
#pragma unroll
        for (int j = 0; j < 8; ++j) {
            int k = kbase + j;
            float w = (sg == 0) ? (W1[(128 + k) * LL1 + n] - W1[(384 + k) * LL1 + n])
                                :  W1[(256 + k) * LL1 + n];
            unsigned short hb = f2bf(w);
            o[j] = (hl == 0) ? hb : f2bf(w - bf2f(hb));
        }
    } else if (blk < 25) {
        int t = (blk - 20) * 256 + threadIdx.x;
        if (t >= 18 * 64) return;
        int lane = t & 63;
        int fid  = t >> 6;
        int hl   = fid & 1;
        int nt   = (fid >> 1) % 3;
        int kt   = fid / 6;
        int n  = nt * 16 + (lane & 15);
        int kb = kt * 32 + (lane >> 4) * 8;
        unsigned short* o = bfr2 + (size_t)t * 8;
#pragma unroll
        for (int j = 0; j < 8; ++j) {
            int k = kb + j;
            float w = (k < LL1 && n < LL2) ? W2[k * LL2 + n] : 0.f;
            unsigned short hb = f2bf(w);
            o[j] = (hl == 0) ? hb : f2bf(w - bf2f(hb));
        }
    } else if (blk == 25) {
        if (threadIdx.x < 64) {
            const uchar4 u = ((const uchar4*)mask)[threadIdx.x];
            const bool f = ((u.y | u.z) | u.w) != 0;
            const unsigned long long anyf = __ballot(f);
            if (threadIdx.x == 0) *flag = (anyf != 0ull) ? 1 : 0;
        }
    } else {
        // U-GEMM: 342 blocks x (3 qr x 80 n)
        const int tid = threadIdx.x;
        if (tid >= 240) return;
        const int qr = (blk - 26) * 3 + tid / 80;
        const int n  = tid % 80;
        if (qr >= 1024) return;
        const float* q = query + (size_t)qr * DD;
        float acc = b1[n];
#pragma unroll 8
        for (int k = 0; k < DD; ++k)
            acc = fmaf(q[k], W1[k * LL1 + n] + W1[(384 + k) * LL1 + n], acc);
        U[(size_t)qr * LL1 + n] = acc;
    }
}

// ---------------------------------------------------------------------------
// K1: z1[p][l] = f·(W1b-W1d) + (q⊙f)·W1c + U[p/200]  — the q-only term is
// precomputed (exact f32) in prep, cutting MFMA/split8 work by 1/3 and the
// per-kt staging from 30 KB to 20 KB. Structure = round-5-verified 4-phase
// single-buffer (best measured: dbuf/no-LDS/global-B all slower, r6/r7).
// Round 2-3 lesson: launch_bounds (.,4) clamps VGPR to 64 and spills;
// (256,2) leaves natural allocation.
__global__ __launch_bounds__(256, 2) void k1_mfma(
    const float* __restrict__ query, const float* __restrict__ facts,
    const unsigned short* __restrict__ bfr, const float* __restrict__ U,
    float* __restrict__ z1) {
    const int tid  = threadIdx.x;
    const int lane = tid & 63;
    const int m    = lane & 15;
    const int quad = lane >> 4;
    const int pw   = blockIdx.x * 128 + (tid >> 6) * 32;

    __shared__ __align__(16) unsigned short lbuf[10240];   // 20480 B: one kt (2 sg)

    f32x4 acc[2][5];
#pragma unroll
    for (int t = 0; t < 2; ++t)
#pragma unroll
        for (int nt = 0; nt < 5; ++nt) acc[t][nt] = (f32x4){0.f, 0.f, 0.f, 0.f};

    int pr[2], qr[2];
#pragma unroll
    for (int t = 0; t < 2; ++t) {
        pr[t] = pw + t * 16 + m;
        qr[t] = pr[t] / SS;
    }

#pragma unroll 1
    for (int kt = 0; kt < 4; ++kt) {
        // A burst-load for this kt (independent of LDS; overlaps barrier wait)
        const int dbase = kt * 32 + quad * 8;
        float q8[2][8], f8[2][8];
#pragma unroll
        for (int t = 0; t < 2; ++t) {
            const float* qp = query + (size_t)qr[t] * DD + dbase;
            const float* fp = facts + (size_t)pr[t] * DD + dbase;
            *(float4*)&q8[t][0] = *(const float4*)qp;
            *(float4*)&q8[t][4] = *(const float4*)(qp + 4);
            *(float4*)&f8[t][0] = *(const float4*)fp;
            *(float4*)&f8[t][4] = *(const float4*)(fp + 4);
        }
        if (kt) __syncthreads();             // previous phase's LDS reads done
        {
            const int4* src = (const int4*)bfr + kt * 1280;
#pragma unroll
            for (int it = 0; it < 5; ++it)   // 1280 int4 = 5 x 256
                ((int4*)lbuf)[it * 256 + tid] = src[it * 256 + tid];
        }
        __syncthreads();

#pragma unroll
        for (int sg = 0; sg < 2; ++sg) {     // sg0: f-term, sg1: (q*f)-term
            bf16x8 Bh[5], Bl[5];
#pragma unroll
            for (int nt = 0; nt < 5; ++nt) {
                Bh[nt] = *(const bf16x8*)&lbuf[((sg * 2 + 0) * 5 + nt) * 512 + lane * 8];
                Bl[nt] = *(const bf16x8*)&lbuf[((sg * 2 + 1) * 5 + nt) * 512 + lane * 8];
            }
#pragma unroll
            for (int t = 0; t < 2; ++t) {
                float x8[8];
#pragma unroll
                for (int j = 0; j < 8; ++j)
                    x8[j] = (sg == 0) ? f8[t][j] : q8[t][j] * f8[t][j];
                bf16x8 ah, al;
                split8(x8, ah, al);
#pragma unroll
                for (int nt = 0; nt < 5; ++nt) {
                    acc[t][nt] = __builtin_amdgcn_mfma_f32_16x16x32_bf16(ah, Bh[nt], acc[t][nt], 0, 0, 0);
                    acc[t][nt] = __builtin_amdgcn_mfma_f32_16x16x32_bf16(al, Bh[nt], acc[t][nt], 0, 0, 0);
                    acc[t][nt] = __builtin_amdgcn_mfma_f32_16x16x32_bf16(ah, Bl[nt], acc[t][nt], 0, 0, 0);
                }
            }
        }
    }
    // C/D layout: col = lane&15, row = quad*4 + reg. Coalesced [p][l] write;
    // add the exact q-term U[p/200][n] (L2-hot) during the store.
#pragma unroll
    for (int t = 0; t < 2; ++t)
#pragma unroll
        for (int r = 0; r < 4; ++r) {
            const int p = pw + t * 16 + quad * 4 + r;
            const float* urow = U + (size_t)(p / SS) * LL1;
#pragma unroll
            for (int nt = 0; nt < 5; ++nt) {
                const int n = nt * 16 + m;
                z1[(size_t)p * LL1 + n] = acc[t][nt][r] + urow[n];
            }
        }
}

// ---------------------------------------------------------------------------
// K_light: per-b tail (single column, 72 KB LDS — round-5-verified,
// unchanged). Stage z1 rows s*1024+b (320 B chunks) -> LDS stride 81,
// stats1 -> dice1+GEMM2 (B2 direct from L2-hot bfr2) -> z2 (stride 41)
// -> stats2 -> dice2 + W3 dot -> masked softmax -> wgt to wbufT.
__global__ __launch_bounds__(512) void k_light(
    const float* __restrict__ z1, const unsigned short* __restrict__ bfr2,
    const float* __restrict__ a1, const float* __restrict__ b2,
    const float* __restrict__ a2, const float* __restrict__ W3,
    const float* __restrict__ b3, const void* __restrict__ mask,
    const int* __restrict__ flag, float* __restrict__ wbufT) {
    const int tid  = threadIdx.x;
    const int w    = tid >> 6;
    const int lane = tid & 63;
    const int m    = lane & 15;
    const int quad = lane >> 4;
    const int b    = blockIdx.x;

    __shared__ __align__(16) float z1f[NTILE * 16 * 81 + 16];  // 208 rows x 81 (+pad)
    __shared__ float psum[480], pssq[480];
    __shared__ float smean[LL1], sistd[LL1];
    __shared__ float sw3[LL2];
    __shared__ float red[8];

    // stage: 200 rows x 5 float4 (320 B contiguous per row) -> stride-81 rows
    {
        for (int i = tid; i < SS * 20; i += 512) {
            const int s = i / 20;
            const int o = i - s * 20;
            float4 v = ((const float4*)z1)[(size_t)(s * BB + b) * 20 + o];
            float* d = &z1f[s * 81 + o * 4];
            d[0] = v.x; d[1] = v.y; d[2] = v.z; d[3] = v.w;
        }
        // zero pad rows 200..207 (read by GEMM2 A-fragments, outputs discarded)
        for (int i = tid; i < 8 * 81 + 16; i += 512) z1f[SS * 81 + i] = 0.f;
    }
    __syncthreads();

    // stats1 over s (per l), 6 chunks x 80 cols
    if (tid < 480) {
        const int l = tid % LL1, c = tid / LL1;
        const int s0 = c * 34;
        const int s1 = (s0 + 34 < SS) ? s0 + 34 : SS;
        float sum = 0.f, ssq = 0.f;
        for (int s = s0; s < s1; ++s) {
            float v = z1f[s * 81 + l];
            sum += v;
            ssq = fmaf(v, v, ssq);
        }
        psum[c * LL1 + l] = sum;
        pssq[c * LL1 + l] = ssq;
    }
    __syncthreads();
    if (tid < LL1) {
        float sum = 0.f, ssq = 0.f;
#pragma unroll
        for (int c = 0; c < 6; ++c) {
            sum += psum[c * LL1 + tid];
            ssq += pssq[c * LL1 + tid];
        }
        float mn  = sum * (1.f / SS);
        float var = (ssq - (float)SS * mn * mn) * (1.f / (SS - 1));
        smean[tid] = mn;
        sistd[tid] = rsqrtf(var);
    }
    __syncthreads();

    // GEMM2: dice1-on-load, K 80->96, N 40->48. 8 waves x 2 tiles {w, w+8}.
    const float alpha1 = *a1;
    f32x4 acc2[2][3];
#pragma unroll
    for (int t = 0; t < 2; ++t)
#pragma unroll
        for (int nt = 0; nt < 3; ++nt) acc2[t][nt] = (f32x4){0.f, 0.f, 0.f, 0.f};

    int tile[2];
    bool tl[2];
#pragma unroll
    for (int t = 0; t < 2; ++t) {
        tile[t] = t * 8 + w;
        tl[t]   = (tile[t] < NTILE);
    }

#pragma unroll
    for (int kt = 0; kt < 3; ++kt) {
        bf16x8 Bh[3], Bl[3];
#pragma unroll
        for (int nt = 0; nt < 3; ++nt) {     // 18 KB, L2-hot, read direct
            Bh[nt] = *(const bf16x8*)(bfr2 + (size_t)((kt * 3 + nt) * 2 + 0) * 512 + lane * 8);
            Bl[nt] = *(const bf16x8*)(bfr2 + (size_t)((kt * 3 + nt) * 2 + 1) * 512 + lane * 8);
        }
        const int kb = kt * 32 + quad * 8;
        const bool lv = (kt < 2 || quad < 2);   // k < 80
#pragma unroll
        for (int t = 0; t < 2; ++t) {
            if (!tl[t]) continue;
            float x8[8];
            if (lv) {
                const float* zr = &z1f[(tile[t] * 16 + m) * 81 + kb];
#pragma unroll
                for (int j = 0; j < 8; ++j) {
                    float v  = zr[j];
                    float pp = fast_sigmoid((v - smean[kb + j]) * sistd[kb + j]);
                    x8[j] = v * (alpha1 + (1.f - alpha1) * pp);
                }
            } else {
#pragma unroll
                for (int j = 0; j < 8; ++j) x8[j] = 0.f;
            }
            bf16x8 ah, al;
            split8(x8, ah, al);
#pragma unroll
            for (int nt = 0; nt < 3; ++nt) {
                acc2[t][nt] = __builtin_amdgcn_mfma_f32_16x16x32_bf16(ah, Bh[nt], acc2[t][nt], 0, 0, 0);
                acc2[t][nt] = __builtin_amdgcn_mfma_f32_16x16x32_bf16(al, Bh[nt], acc2[t][nt], 0, 0, 0);
                acc2[t][nt] = __builtin_amdgcn_mfma_f32_16x16x32_bf16(ah, Bl[nt], acc2[t][nt], 0, 0, 0);
            }
        }
    }
    __syncthreads();                         // all z1 reads done -> reuse as z2

    {
        float b2v[3];
#pragma unroll
        for (int nt = 0; nt < 3; ++nt) {
            const int n = nt * 16 + m;
            b2v[nt] = (n < LL2) ? b2[n] : 0.f;
        }
#pragma unroll
        for (int t = 0; t < 2; ++t) {
            if (!tl[t]) continue;
#pragma unroll
            for (int r = 0; r < 4; ++r) {
                const int srow = tile[t] * 16 + quad * 4 + r;
                if (srow >= SS) continue;
#pragma unroll
                for (int nt = 0; nt < 3; ++nt) {
                    const int n = nt * 16 + m;
                    if (n < LL2) z1f[srow * 41 + n] = acc2[t][nt][r] + b2v[nt];
                }
            }
        }
    }
    __syncthreads();

    // stats2, 12 chunks x 40 cols
    if (tid < 480) {
        const int l = tid % LL2, c = tid / LL2;
        const int s0 = c * 17;
        const int s1 = (s0 + 17 < SS) ? s0 + 17 : SS;
        float sum = 0.f, ssq = 0.f;
        for (int s = s0; s < s1; ++s) {
            float v = z1f[s * 41 + l];
            sum += v;
            ssq = fmaf(v, v, ssq);
        }
        psum[c * LL2 + l] = sum;
        pssq[c * LL2 + l] = ssq;
    }
    __syncthreads();
    if (tid < LL2) {
        float sum = 0.f, ssq = 0.f;
#pragma unroll
        for (int c = 0; c < 12; ++c) {
            sum += psum[c * LL2 + tid];
            ssq += pssq[c * LL2 + tid];
        }
        float mn  = sum * (1.f / SS);
        float var = (ssq - (float)SS * mn * mn) * (1.f / (SS - 1));
        smean[tid] = mn;
        sistd[tid] = rsqrtf(var);
        sw3[tid]   = W3[tid];
    }
    __syncthreads();

    // dice2 + W3 dot + masked softmax over s
    const float alpha2 = *a2;
    const int boolLayout = *flag;
    float logit = -3.0e38f;
    if (tid < SS) {
        float dot = b3[0];
#pragma unroll
        for (int k = 0; k < LL2; ++k) {
            float v  = z1f[tid * 41 + k];
            float pp = fast_sigmoid((v - smean[k]) * sistd[k]);
            float hh = v * (pp + alpha2 * (1.f - pp));
            dot = fmaf(hh, sw3[k], dot);
        }
        const int mi = tid * BB + b;
        const bool mk = boolLayout ? (((const unsigned char*)mask)[mi] != 0)
                                   : (((const int*)mask)[mi] != 0);
        logit = mk ? dot : MASK_FILL_F;
    }
    float v = logit;
#pragma unroll
    for (int off = 1; off < 64; off <<= 1) v = fmaxf(v, __shfl_xor(v, off, 64));
    if (lane == 0) red[w] = v;
    __syncthreads();
    float smax = red[0];
#pragma unroll
    for (int i = 1; i < 8; ++i) smax = fmaxf(smax, red[i]);
    __syncthreads();
    const float e = (tid < SS) ? __expf(logit - smax) : 0.f;
    v = e;
#pragma unroll
    for (int off = 1; off < 64; off <<= 1) v += __shfl_xor(v, off, 64);
    if (lane == 0) red[w] = v;
    __syncthreads();
    float ssum = red[0];
#pragma unroll
    for (int i = 1; i < 8; ++i) ssum += red[i];
    const float inv = __builtin_amdgcn_rcpf(ssum);
    if (tid < SS) wbufT[(size_t)b * SS + tid] = e * inv;
}

// ---------------------------------------------------------------------------
// K4: out[s][b][d] = wbufT[b][s] * facts[s][b][d]  (fully coalesced stream)
__global__ __launch_bounds__(256) void k4_scale(
    const float* __restrict__ wbufT, const float* __restrict__ facts,
    float* __restrict__ out) {
    int i = blockIdx.x * 256 + threadIdx.x;   // float4 index
    int p = i >> 5;                           // (s*B + b), 32 float4 per row
    float w = wbufT[(size_t)(p & (BB - 1)) * SS + (p >> 10)];
    float4 f = ((const float4*)facts)[i];
    float4 o;
    o.x = f.x * w; o.y = f.y * w; o.z = f.z * w; o.w = f.w * w;
    ((float4*)out)[i] = o;
}

// ---------------------------------------------------------------------------
extern "C" void kernel_launch(void* const* d_in, const int* in_sizes, int n_in,
                              void* d_out, int out_size, void* d_ws, size_t ws_size,
                              hipStream_t stream) {
    const float* query = (const float*)d_in[0];
    const float* facts = (const float*)d_in[1];
    const void*  mask  = d_in[2];
    const float* W1 = (const float*)d_in[3];
    const float* b1 = (const float*)d_in[4];
    const float* a1 = (const float*)d_in[5];
    const float* W2 = (const float*)d_in[6];
    const float* b2 = (const float*)d_in[7];
    const float* a2 = (const float*)d_in[8];
    const float* W3 = (const float*)d_in[9];
    const float* b3 = (const float*)d_in[10];
    float* out = (float*)d_out;

    // d_out scratch (26,214,400 floats; all dead before k4 overwrites):
    //   z1 [0, 16,384,000)  layout [p][l]
    //   U    @ float-offset 24,600,000 (81,920 floats, ends 24,681,920)
    //   bfr1 @ 24,739,840 (81,920 B = 20,480 floats)
    //   bfr2 @ 24,801,280 (18,432 B)
    float* z1 = out;
    float* U  = out + 24600000;
    unsigned short* bfr1 = (unsigned short*)(out + 24739840);
    unsigned short* bfr2 = (unsigned short*)(out + 24801280);
    // d_ws: wbufT (819,200 B) @0 ; flag @900K
    float* wbufT = (float*)d_ws;
    int*   flag  = (int*)((char*)d_ws + 900 * 1024);

    k_prep_all<<<368, 256, 0, stream>>>(W1, W2, (const unsigned char*)mask,
                                        query, b1, bfr1, bfr2, U, flag);
    k1_mfma<<<PP / 128, 256, 0, stream>>>(query, facts, bfr1, U, z1);
    k_light<<<BB, 512, 0, stream>>>(z1, bfr2, a1, b2, a2, W3, b3, mask, flag, wbufT);
    k4_scale<<<(PP * DD) / (256 * 4), 256, 0, stream>>>(wbufT, facts, out);
}

// Round 9
// 298.284 us; speedup vs baseline: 1.0987x; 1.0020x over previous
//
#include <hip/hip_runtime.h>
#include <hip/hip_bf16.h>
#include <math.h>

#define SS 200
#define BB 1024
#define DD 128
#define FF 512
#define LL1 80
#define LL2 40
#define PP (SS*BB)
#define MASK_FILL_F (-4294967295.0f)
#define NTILE 13            // 13 s-tiles of 16 rows = 208 (200 live)

typedef short bf16x8 __attribute__((ext_vector_type(8)));
typedef float f32x4  __attribute__((ext_vector_type(4)));

static __device__ __forceinline__ unsigned short f2bf(float x) {
    __hip_bfloat16 h = __float2bfloat16(x);
    return *reinterpret_cast<unsigned short*>(&h);
}
static __device__ __forceinline__ float bf2f(unsigned short u) {
    __hip_bfloat16 h = *reinterpret_cast<__hip_bfloat16*>(&u);
    return __bfloat162float(h);
}
// truncation split: hi = top 16 bits, lo = bf16(x - hi). |err| ~ 2^-16 rel.
static __device__ __forceinline__ void split8(const float* x, bf16x8& ah, bf16x8& al) {
#pragma unroll
    for (int j = 0; j < 8; ++j) {
        unsigned u = __float_as_uint(x[j]);
        ah[j] = (short)(u >> 16);
        float hi = __uint_as_float(u & 0xffff0000u);
        al[j] = (short)f2bf(x[j] - hi);
    }
}
static __device__ __forceinline__ float fast_sigmoid(float t) {
    return __builtin_amdgcn_rcpf(1.f + __expf(-t));
}

// ---------------------------------------------------------------------------
// Merged prep.
//  blocks 0-19 : W1 fold+split -> bfr1, segs {f, q*f} only (q-part moves to U):
//                fid = kt*20 + (sg*2+hl)*5 + nt ; sg0: W1b-W1d, sg1: W1c
//  blocks 20-24: W2 pad+split -> bfr2, fid2 = (kt*3+nt)*2+hl
//  block  25   : mask layout detect (wave-parallel)
//  blocks 26+  : U[qr][n] = b1[n] + sum_k q[qr][k]*(W1a+W1d)[k][n]  (f32 exact)
__global__ void k_prep_all(const float* __restrict__ W1, const float* __restrict__ W2,
                           const unsigned char* __restrict__ mask,
                           const float* __restrict__ query, const float* __restrict__ b1,
                           unsigned short* __restrict__ bfr1,
                           unsigned short* __restrict__ bfr2,
                           float* __restrict__ U, int* __restrict__ flag) {
    const int blk = blockIdx.x;
    if (blk < 20) {
        int t = blk * 256 + threadIdx.x;     // 80 fids x 64 lanes = 5120 threads
        int lane = t & 63;
        int fid  = t >> 6;
        int nt = fid % 5;
        int hl = (fid / 5) % 2;
        int sg = (fid / 10) % 2;
        int kt = fid / 20;
        int n     = nt * 16 + (lane & 15);
        int kbase = kt * 32 + (lane >> 4) * 8;
        unsigned short* o = bfr1 + (size_t)t * 8;
#pragma unroll
        for (int j = 0; j < 8; ++j) {
            int k = kbase + j;
            float w = (sg == 0) ? (W1[(128 + k) * LL1 + n] - W1[(384 + k) * LL1 + n])
                                :  W1[(256 + k) * LL1 + n];
            unsigned short hb = f2bf(w);
            o[j] = (hl == 0) ? hb : f2bf(w - bf2f(hb));
        }
    } else if (blk < 25) {
        int t = (blk - 20) * 256 + threadIdx.x;
        if (t >= 18 * 64) return;
        int lane = t & 63;
        int fid  = t >> 6;
        int hl   = fid & 1;
        int nt   = (fid >> 1) % 3;
        int kt   = fid / 6;
        int n  = nt * 16 + (lane & 15);
        int kb = kt * 32 + (lane >> 4) * 8;
        unsigned short* o = bfr2 + (size_t)t * 8;
#pragma unroll
        for (int j = 0; j < 8; ++j) {
            int k = kb + j;
            float w = (k < LL1 && n < LL2) ? W2[k * LL2 + n] : 0.f;
            unsigned short hb = f2bf(w);
            o[j] = (hl == 0) ? hb : f2bf(w - bf2f(hb));
        }
    } else if (blk == 25) {
        if (threadIdx.x < 64) {
            const uchar4 u = ((const uchar4*)mask)[threadIdx.x];
            const bool f = ((u.y | u.z) | u.w) != 0;
            const unsigned long long anyf = __ballot(f);
            if (threadIdx.x == 0) *flag = (anyf != 0ull) ? 1 : 0;
        }
    } else {
        // U-GEMM: 342 blocks x (3 qr x 80 n)
        const int tid = threadIdx.x;
        if (tid >= 240) return;
        const int qr = (blk - 26) * 3 + tid / 80;
        const int n  = tid % 80;
        if (qr >= 1024) return;
        const float* q = query + (size_t)qr * DD;
        float acc = b1[n];
#pragma unroll 8
        for (int k = 0; k < DD; ++k)
            acc = fmaf(q[k], W1[k * LL1 + n] + W1[(384 + k) * LL1 + n], acc);
        U[(size_t)qr * LL1 + n] = acc;
    }
}

// ---------------------------------------------------------------------------
// K1: z1[p][l] = f·(W1b-W1d) + (q⊙f)·W1c + U[p/200]. STAGE-ONCE design:
// the whole 80-KB bfr1 is loaded into LDS up front (one barrier), then all
// 4 kt phases run with ZERO barriers — A(kt+1) register-prefetched under
// compute(kt). This removes 7 of 8 per-loop vmcnt(0) barrier drains (the
// round-5/8 structure's serializer) without round-7's double-buffer
// occupancy cost. LDS 80 KB -> 2 blocks/CU (8 waves/CU).
// Round 2-3 lesson: launch_bounds (.,4) clamps VGPR to 64 and spills;
// (256,2) leaves natural allocation. Spill tripwire: WRITE_SIZE == 64 MB.
__global__ __launch_bounds__(256, 2) void k1_mfma(
    const float* __restrict__ query, const float* __restrict__ facts,
    const unsigned short* __restrict__ bfr, const float* __restrict__ U,
    float* __restrict__ z1) {
    const int tid  = threadIdx.x;
    const int lane = tid & 63;
    const int m    = lane & 15;
    const int quad = lane >> 4;
    const int pw   = blockIdx.x * 128 + (tid >> 6) * 32;

    __shared__ __align__(16) unsigned short lbuf[40960];   // 81920 B: ALL of bfr1

    f32x4 acc[2][5];
#pragma unroll
    for (int t = 0; t < 2; ++t)
#pragma unroll
        for (int nt = 0; nt < 5; ++nt) acc[t][nt] = (f32x4){0.f, 0.f, 0.f, 0.f};

    int pr[2], qr[2];
#pragma unroll
    for (int t = 0; t < 2; ++t) {
        pr[t] = pw + t * 16 + m;
        qr[t] = pr[t] / SS;
    }

    // stage ALL B-frags once: 5120 int4, 20 per thread (coalesced)
    {
        const int4* src = (const int4*)bfr;
        int4* dst = (int4*)lbuf;
#pragma unroll 5
        for (int it = 0; it < 20; ++it)
            dst[it * 256 + tid] = src[it * 256 + tid];
    }
    // A(0) loads issued before the barrier — land during the barrier wait
    float q8[2][8], f8[2][8];
    {
        const int dbase = quad * 8;
#pragma unroll
        for (int t = 0; t < 2; ++t) {
            const float* qp = query + (size_t)qr[t] * DD + dbase;
            const float* fp = facts + (size_t)pr[t] * DD + dbase;
            *(float4*)&q8[t][0] = *(const float4*)qp;
            *(float4*)&q8[t][4] = *(const float4*)(qp + 4);
            *(float4*)&f8[t][0] = *(const float4*)fp;
            *(float4*)&f8[t][4] = *(const float4*)(fp + 4);
        }
    }
    __syncthreads();                         // the ONLY barrier

#pragma unroll 1
    for (int kt = 0; kt < 4; ++kt) {
        float qn[2][8], fn[2][8];
        if (kt < 3) {
            // A(kt+1) register prefetch — lands under compute(kt)
            const int dbase = (kt + 1) * 32 + quad * 8;
#pragma unroll
            for (int t = 0; t < 2; ++t) {
                const float* qp = query + (size_t)qr[t] * DD + dbase;
                const float* fp = facts + (size_t)pr[t] * DD + dbase;
                *(float4*)&qn[t][0] = *(const float4*)qp;
                *(float4*)&qn[t][4] = *(const float4*)(qp + 4);
                *(float4*)&fn[t][0] = *(const float4*)fp;
                *(float4*)&fn[t][4] = *(const float4*)(fp + 4);
            }
        }
        const unsigned short* cb = lbuf + kt * 10240;   // 20480 B per kt
#pragma unroll
        for (int sg = 0; sg < 2; ++sg) {     // sg0: f-term, sg1: (q*f)-term
            bf16x8 Bh[5], Bl[5];
#pragma unroll
            for (int nt = 0; nt < 5; ++nt) {
                Bh[nt] = *(const bf16x8*)&cb[((sg * 2 + 0) * 5 + nt) * 512 + lane * 8];
                Bl[nt] = *(const bf16x8*)&cb[((sg * 2 + 1) * 5 + nt) * 512 + lane * 8];
            }
#pragma unroll
            for (int t = 0; t < 2; ++t) {
                float x8[8];
#pragma unroll
                for (int j = 0; j < 8; ++j)
                    x8[j] = (sg == 0) ? f8[t][j] : q8[t][j] * f8[t][j];
                bf16x8 ah, al;
                split8(x8, ah, al);
#pragma unroll
                for (int nt = 0; nt < 5; ++nt) {
                    acc[t][nt] = __builtin_amdgcn_mfma_f32_16x16x32_bf16(ah, Bh[nt], acc[t][nt], 0, 0, 0);
                    acc[t][nt] = __builtin_amdgcn_mfma_f32_16x16x32_bf16(al, Bh[nt], acc[t][nt], 0, 0, 0);
                    acc[t][nt] = __builtin_amdgcn_mfma_f32_16x16x32_bf16(ah, Bl[nt], acc[t][nt], 0, 0, 0);
                }
            }
        }
        if (kt < 3) {
#pragma unroll
            for (int t = 0; t < 2; ++t)
#pragma unroll
                for (int j = 0; j < 8; ++j) {
                    q8[t][j] = qn[t][j];
                    f8[t][j] = fn[t][j];
                }
        }
    }
    // C/D layout: col = lane&15, row = quad*4 + reg. Coalesced [p][l] write;
    // add the exact q-term U[p/200][n] (L2-hot) during the store.
#pragma unroll
    for (int t = 0; t < 2; ++t)
#pragma unroll
        for (int r = 0; r < 4; ++r) {
            const int p = pw + t * 16 + quad * 4 + r;
            const float* urow = U + (size_t)(p / SS) * LL1;
#pragma unroll
            for (int nt = 0; nt < 5; ++nt) {
                const int n = nt * 16 + m;
                z1[(size_t)p * LL1 + n] = acc[t][nt][r] + urow[n];
            }
        }
}

// ---------------------------------------------------------------------------
// K_light: per-b tail (single column, 72 KB LDS — round-5-verified,
// unchanged). Stage z1 rows s*1024+b (320 B chunks) -> LDS stride 81,
// stats1 -> dice1+GEMM2 (B2 direct from L2-hot bfr2) -> z2 (stride 41)
// -> stats2 -> dice2 + W3 dot -> masked softmax -> wgt to wbufT.
__global__ __launch_bounds__(512) void k_light(
    const float* __restrict__ z1, const unsigned short* __restrict__ bfr2,
    const float* __restrict__ a1, const float* __restrict__ b2,
    const float* __restrict__ a2, const float* __restrict__ W3,
    const float* __restrict__ b3, const void* __restrict__ mask,
    const int* __restrict__ flag, float* __restrict__ wbufT) {
    const int tid  = threadIdx.x;
    const int w    = tid >> 6;
    const int lane = tid & 63;
    const int m    = lane & 15;
    const int quad = lane >> 4;
    const int b    = blockIdx.x;

    __shared__ __align__(16) float z1f[NTILE * 16 * 81 + 16];  // 208 rows x 81 (+pad)
    __shared__ float psum[480], pssq[480];
    __shared__ float smean[LL1], sistd[LL1];
    __shared__ float sw3[LL2];
    __shared__ float red[8];

    // stage: 200 rows x 5 float4 (320 B contiguous per row) -> stride-81 rows
    {
        for (int i = tid; i < SS * 20; i += 512) {
            const int s = i / 20;
            const int o = i - s * 20;
            float4 v = ((const float4*)z1)[(size_t)(s * BB + b) * 20 + o];
            float* d = &z1f[s * 81 + o * 4];
            d[0] = v.x; d[1] = v.y; d[2] = v.z; d[3] = v.w;
        }
        // zero pad rows 200..207 (read by GEMM2 A-fragments, outputs discarded)
        for (int i = tid; i < 8 * 81 + 16; i += 512) z1f[SS * 81 + i] = 0.f;
    }
    __syncthreads();

    // stats1 over s (per l), 6 chunks x 80 cols
    if (tid < 480) {
        const int l = tid % LL1, c = tid / LL1;
        const int s0 = c * 34;
        const int s1 = (s0 + 34 < SS) ? s0 + 34 : SS;
        float sum = 0.f, ssq = 0.f;
        for (int s = s0; s < s1; ++s) {
            float v = z1f[s * 81 + l];
            sum += v;
            ssq = fmaf(v, v, ssq);
        }
        psum[c * LL1 + l] = sum;
        pssq[c * LL1 + l] = ssq;
    }
    __syncthreads();
    if (tid < LL1) {
        float sum = 0.f, ssq = 0.f;
#pragma unroll
        for (int c = 0; c < 6; ++c) {
            sum += psum[c * LL1 + tid];
            ssq += pssq[c * LL1 + tid];
        }
        float mn  = sum * (1.f / SS);
        float var = (ssq - (float)SS * mn * mn) * (1.f / (SS - 1));
        smean[tid] = mn;
        sistd[tid] = rsqrtf(var);
    }
    __syncthreads();

    // GEMM2: dice1-on-load, K 80->96, N 40->48. 8 waves x 2 tiles {w, w+8}.
    const float alpha1 = *a1;
    f32x4 acc2[2][3];
#pragma unroll
    for (int t = 0; t < 2; ++t)
#pragma unroll
        for (int nt = 0; nt < 3; ++nt) acc2[t][nt] = (f32x4){0.f, 0.f, 0.f, 0.f};

    int tile[2];
    bool tl[2];
#pragma unroll
    for (int t = 0; t < 2; ++t) {
        tile[t] = t * 8 + w;
        tl[t]   = (tile[t] < NTILE);
    }

#pragma unroll
    for (int kt = 0; kt < 3; ++kt) {
        bf16x8 Bh[3], Bl[3];
#pragma unroll
        for (int nt = 0; nt < 3; ++nt) {     // 18 KB, L2-hot, read direct
            Bh[nt] = *(const bf16x8*)(bfr2 + (size_t)((kt * 3 + nt) * 2 + 0) * 512 + lane * 8);
            Bl[nt] = *(const bf16x8*)(bfr2 + (size_t)((kt * 3 + nt) * 2 + 1) * 512 + lane * 8);
        }
        const int kb = kt * 32 + quad * 8;
        const bool lv = (kt < 2 || quad < 2);   // k < 80
#pragma unroll
        for (int t = 0; t < 2; ++t) {
            if (!tl[t]) continue;
            float x8[8];
            if (lv) {
                const float* zr = &z1f[(tile[t] * 16 + m) * 81 + kb];
#pragma unroll
                for (int j = 0; j < 8; ++j) {
                    float v  = zr[j];
                    float pp = fast_sigmoid((v - smean[kb + j]) * sistd[kb + j]);
                    x8[j] = v * (alpha1 + (1.f - alpha1) * pp);
                }
            } else {
#pragma unroll
                for (int j = 0; j < 8; ++j) x8[j] = 0.f;
            }
            bf16x8 ah, al;
            split8(x8, ah, al);
#pragma unroll
            for (int nt = 0; nt < 3; ++nt) {
                acc2[t][nt] = __builtin_amdgcn_mfma_f32_16x16x32_bf16(ah, Bh[nt], acc2[t][nt], 0, 0, 0);
                acc2[t][nt] = __builtin_amdgcn_mfma_f32_16x16x32_bf16(al, Bh[nt], acc2[t][nt], 0, 0, 0);
                acc2[t][nt] = __builtin_amdgcn_mfma_f32_16x16x32_bf16(ah, Bl[nt], acc2[t][nt], 0, 0, 0);
            }
        }
    }
    __syncthreads();                         // all z1 reads done -> reuse as z2

    {
        float b2v[3];
#pragma unroll
        for (int nt = 0; nt < 3; ++nt) {
            const int n = nt * 16 + m;
            b2v[nt] = (n < LL2) ? b2[n] : 0.f;
        }
#pragma unroll
        for (int t = 0; t < 2; ++t) {
            if (!tl[t]) continue;
#pragma unroll
            for (int r = 0; r < 4; ++r) {
                const int srow = tile[t] * 16 + quad * 4 + r;
                if (srow >= SS) continue;
#pragma unroll
                for (int nt = 0; nt < 3; ++nt) {
                    const int n = nt * 16 + m;
                    if (n < LL2) z1f[srow * 41 + n] = acc2[t][nt][r] + b2v[nt];
                }
            }
        }
    }
    __syncthreads();

    // stats2, 12 chunks x 40 cols
    if (tid < 480) {
        const int l = tid % LL2, c = tid / LL2;
        const int s0 = c * 17;
        const int s1 = (s0 + 17 < SS) ? s0 + 17 : SS;
        float sum = 0.f, ssq = 0.f;
        for (int s = s0; s < s1; ++s) {
            float v = z1f[s * 41 + l];
            sum += v;
            ssq = fmaf(v, v, ssq);
        }
        psum[c * LL2 + l] = sum;
        pssq[c * LL2 + l] = ssq;
    }
    __syncthreads();
    if (tid < LL2) {
        float sum = 0.f, ssq = 0.f;
#pragma unroll
        for (int c = 0; c < 12; ++c) {
            sum += psum[c * LL2 + tid];
            ssq += pssq[c * LL2 + tid];
        }
        float mn  = sum * (1.f / SS);
        float var = (ssq - (float)SS * mn * mn) * (1.f / (SS - 1));
        smean[tid] = mn;
        sistd[tid] = rsqrtf(var);
        sw3[tid]   = W3[tid];
    }
    __syncthreads();

    // dice2 + W3 dot + masked softmax over s
    const float alpha2 = *a2;
    const int boolLayout = *flag;
    float logit = -3.0e38f;
    if (tid < SS) {
        float dot = b3[0];
#pragma unroll
        for (int k = 0; k < LL2; ++k) {
            float v  = z1f[tid * 41 + k];
            float pp = fast_sigmoid((v - smean[k]) * sistd[k]);
            float hh = v * (pp + alpha2 * (1.f - pp));
            dot = fmaf(hh, sw3[k], dot);
        }
        const int mi = tid * BB + b;
        const bool mk = boolLayout ? (((const unsigned char*)mask)[mi] != 0)
                                   : (((const int*)mask)[mi] != 0);
        logit = mk ? dot : MASK_FILL_F;
    }
    float v = logit;
#pragma unroll
    for (int off = 1; off < 64; off <<= 1) v = fmaxf(v, __shfl_xor(v, off, 64));
    if (lane == 0) red[w] = v;
    __syncthreads();
    float smax = red[0];
#pragma unroll
    for (int i = 1; i < 8; ++i) smax = fmaxf(smax, red[i]);
    __syncthreads();
    const float e = (tid < SS) ? __expf(logit - smax) : 0.f;
    v = e;
#pragma unroll
    for (int off = 1; off < 64; off <<= 1) v += __shfl_xor(v, off, 64);
    if (lane == 0) red[w] = v;
    __syncthreads();
    float ssum = red[0];
#pragma unroll
    for (int i = 1; i < 8; ++i) ssum += red[i];
    const float inv = __builtin_amdgcn_rcpf(ssum);
    if (tid < SS) wbufT[(size_t)b * SS + tid] = e * inv;
}

// ---------------------------------------------------------------------------
// K4: out[s][b][d] = wbufT[b][s] * facts[s][b][d]  (fully coalesced stream)
__global__ __launch_bounds__(256) void k4_scale(
    const float* __restrict__ wbufT, const float* __restrict__ facts,
    float* __restrict__ out) {
    int i = blockIdx.x * 256 + threadIdx.x;   // float4 index
    int p = i >> 5;                           // (s*B + b), 32 float4 per row
    float w = wbufT[(size_t)(p & (BB - 1)) * SS + (p >> 10)];
    float4 f = ((const float4*)facts)[i];
    float4 o;
    o.x = f.x * w; o.y = f.y * w; o.z = f.z * w; o.w = f.w * w;
    ((float4*)out)[i] = o;
}

// ---------------------------------------------------------------------------
extern "C" void kernel_launch(void* const* d_in, const int* in_sizes, int n_in,
                              void* d_out, int out_size, void* d_ws, size_t ws_size,
                              hipStream_t stream) {
    const float* query = (const float*)d_in[0];
    const float* facts = (const float*)d_in[1];
    const void*  mask  = d_in[2];
    const float* W1 = (const float*)d_in[3];
    const float* b1 = (const float*)d_in[4];
    const float* a1 = (const float*)d_in[5];
    const float* W2 = (const float*)d_in[6];
    const float* b2 = (const float*)d_in[7];
    const float* a2 = (const float*)d_in[8];
    const float* W3 = (const float*)d_in[9];
    const float* b3 = (const float*)d_in[10];
    float* out = (float*)d_out;

    // d_out scratch (26,214,400 floats; all dead before k4 overwrites):
    //   z1 [0, 16,384,000)  layout [p][l]
    //   U    @ float-offset 24,600,000 (81,920 floats)
    //   bfr1 @ 24,739,840 (81,920 B) ; bfr2 @ 24,801,280 (18,432 B)
    float* z1 = out;
    float* U  = out + 24600000;
    unsigned short* bfr1 = (unsigned short*)(out + 24739840);
    unsigned short* bfr2 = (unsigned short*)(out + 24801280);
    // d_ws: wbufT (819,200 B) @0 ; flag @900K
    float* wbufT = (float*)d_ws;
    int*   flag  = (int*)((char*)d_ws + 900 * 1024);

    k_prep_all<<<368, 256, 0, stream>>>(W1, W2, (const unsigned char*)mask,
                                        query, b1, bfr1, bfr2, U, flag);
    k1_mfma<<<PP / 128, 256, 0, stream>>>(query, facts, bfr1, U, z1);
    k_light<<<BB, 512, 0, stream>>>(z1, bfr2, a1, b2, a2, W3, b3, mask, flag, wbufT);
    k4_scale<<<(PP * DD) / (256 * 4), 256, 0, stream>>>(wbufT, facts, out);
}